// Round 19
// baseline (271.716 us; speedup 1.0000x reference)
//
#include <hip/hip_runtime.h>

typedef _Float16 v8h __attribute__((ext_vector_type(8)));
typedef _Float16 v4h __attribute__((ext_vector_type(4)));
typedef float    v4f __attribute__((ext_vector_type(4)));

template<int V> struct IC { static constexpr int value = V; };

__device__ __forceinline__ float fast_tanh(float x) {
    float e = __expf(2.0f * x);
    return 1.0f - 2.0f * __builtin_amdgcn_rcpf(e + 1.0f);
}

// ---------------------------------------------------------------------------
// pack layout (halves), unchanged from r17/r18:
//  FWD hidden:  idx = ((((pipe*3+l)*8 + nt)*4 + kk)*64 + lane)*8 + j   [0, 98304)
//  BWD hidden (transposed A-frags):  98304 + same indexing             [98304, 196608)
//  GRADWIN:     196608 + ((pipe*4 + kk)*64 + lane)*8 + j               [196608, 200704)
// ---------------------------------------------------------------------------
__global__ void pack_weights(const float* __restrict__ dpWh,
                             const float* __restrict__ icWh,
                             const float* __restrict__ dpWin,
                             const float* __restrict__ icWin,
                             _Float16* __restrict__ out) {
    int idx = blockIdx.x * 256 + threadIdx.x;
    if (idx < 98304) {
        int j    = idx & 7;
        int lane = (idx >> 3) & 63;
        int kk   = (idx >> 9) & 3;
        int nt   = (idx >> 11) & 7;
        int lp   = idx >> 14;           // 0..5
        int l    = lp % 3;
        const float* src = (lp >= 3) ? icWh : dpWh;
        int k = kk * 32 + (lane >> 4) * 8 + j;
        int n = nt * 16 + (lane & 15);
        out[idx] = (_Float16)src[(l * 128 + k) * 128 + n];
    } else if (idx < 196608) {
        int f    = idx - 98304;
        int j    = f & 7;
        int lane = (f >> 3) & 63;
        int kk   = (f >> 9) & 3;
        int nt   = (f >> 11) & 7;
        int lp   = f >> 14;
        int l    = lp % 3;
        const float* src = (lp >= 3) ? icWh : dpWh;
        int fr = nt * 16 + (lane & 15);
        int g  = kk * 32 + (lane >> 4) * 8 + j;
        out[idx] = (_Float16)src[(l * 128 + fr) * 128 + g];
    } else if (idx < 200704) {
        int f    = idx - 196608;
        int j    = f & 7;
        int lane = (f >> 3) & 63;
        int kk   = (f >> 9) & 3;
        int pipe = (f >> 11) & 1;
        int m = lane & 15;
        int k = kk * 32 + (lane >> 4) * 8 + j;
        float v = 0.0f;
        if (m < 3) v = pipe ? icWin[m * 128 + k] : dpWin[(m + 1) * 128 + k];
        out[idx] = (_Float16)v;
    }
}

__global__ void sph_prep(const float* __restrict__ tx, float* __restrict__ sph, int N) {
    int row = blockIdx.x * 256 + threadIdx.x;
    if (row >= N) return;
    float4 q = ((const float4*)tx)[row];
    float x = q.y, y = q.z, z = q.w;
    float r  = sqrtf(x * x + y * y + z * z + 1e-12f);
    float uc = fminf(1.0f, fmaxf(-1.0f, z / r));
    ((float4*)sph)[row] = make_float4(q.x, r, acosf(uc), atan2f(y, x));
}

// LDS per block (31232 B -> 5 blocks/CU = 20 waves/CU, 5 barrier domains):
//   H0,H1,H2,GA,GB : 5 x 16 rows x ROWH halves (4352 B each)
//   btab f32[8][128], winb f32[8][128], woutb f32[2][128], vbuf f32[4][16]
#define ROWH 136
#define HBYTES 4352
#define SMEM_BYTES 31232
#define PACK_BYTES 401408   // 200704 halves

__launch_bounds__(256, 2)
__global__ void node_main(const float* __restrict__ sph,
                          const float* __restrict__ dpBin, const float* __restrict__ dpBh,
                          const float* __restrict__ icBin, const float* __restrict__ icBh,
                          const float* __restrict__ dpWin, const float* __restrict__ icWin,
                          const float* __restrict__ dpWout, const float* __restrict__ icWout,
                          const _Float16* __restrict__ pack,
                          float* __restrict__ part, int N)
{
    extern __shared__ char smem[];
    _Float16* H0 = (_Float16*)smem;
    _Float16* H1 = (_Float16*)(smem + HBYTES);
    _Float16* H2 = (_Float16*)(smem + 2 * HBYTES);
    _Float16* GA = (_Float16*)(smem + 3 * HBYTES);
    _Float16* GB = (_Float16*)(smem + 4 * HBYTES);
    float* btab  = (float*)(smem + 5 * HBYTES);
    float* winb  = (float*)(smem + 5 * HBYTES + 4096);
    float* woutb = (float*)(smem + 5 * HBYTES + 8192);
    float* vbuf  = (float*)(smem + 5 * HBYTES + 9216);

    const int tid  = threadIdx.x;
    const int wave = tid >> 6;          // 0..3 = 32-feature slice cg
    const int lane = tid & 63;
    const int l15  = lane & 15;
    const int s    = lane >> 4;         // 0..3 (C rows s*4+j)
    const int cg   = wave;
    const int fb   = cg * 32 + s * 4;   // C-row feature base (subslice 0)
    const int f8   = cg * 32 + s * 8;   // L0: 8 features/thread (s<2 path uses s*8<32)

    for (int i = tid; i < 1024; i += 256) {
        int row = i >> 7, col = i & 127;
        float bv, wv;
        if      (row == 0) bv = dpBin[col];
        else if (row <  4) bv = dpBh[(row - 1) * 128 + col];
        else if (row == 4) bv = icBin[col];
        else               bv = icBh[(row - 5) * 128 + col];
        if      (row <  4) wv = dpWin[row * 128 + col];
        else if (row <  7) wv = icWin[(row - 4) * 128 + col];
        else               wv = 0.0f;
        btab[i] = bv;
        winb[i] = wv;
    }
    woutb[tid] = (tid < 128) ? dpWout[tid] : icWout[tid - 128];
    __syncthreads();

    // static bases
    const int rdo = l15 * ROWH + s * 8;        // B-frag read offset
    const int epo = l15 * ROWH + fb;           // epilogue / h-read offset
    const float NP0 = 1.0f - 0.7745966692414834f;
    const float NP2 = 1.0f + 0.7745966692414834f;

    const int nun = (((N + 15) >> 4) << 2);
    for (int u = blockIdx.x; u < nun; u += gridDim.x) {
        const int chunk = u >> 2;
        const int set   = u & 3;
        const bool isic = (set == 3);
        const int boff  = isic ? 512 : 0;
        const int pipe3 = isic ? 3 : 0;

        // ---- L0: h1 = tanh(Win x + b), 16 rows; thread owns 8 feats of row l15
        //      (s in 0..3: features cg*32 + s*8 .. +7 -> wait s*8 max 24+7=31 OK)
        {
            v4f w0a = *(const v4f*)(winb + boff + f8),       w0b = *(const v4f*)(winb + boff + f8 + 4);
            v4f w1a = *(const v4f*)(winb + boff + 128 + f8), w1b = *(const v4f*)(winb + boff + 128 + f8 + 4);
            v4f w2a = *(const v4f*)(winb + boff + 256 + f8), w2b = *(const v4f*)(winb + boff + 256 + f8 + 4);
            v4f w3a = *(const v4f*)(winb + boff + 384 + f8), w3b = *(const v4f*)(winb + boff + 384 + f8 + 4);
            float np1 = (set == 0) ? NP0 : ((set == 1) ? 1.0f : NP2);
            int row = chunk * 16 + l15;
            float4 sp = (row < N) ? ((const float4*)sph)[row] : make_float4(0.f, 1.f, 1.f, 1.f);
            float i0, i1, i2, i3;
            if (isic) { i0 = sp.y; i1 = sp.z; i2 = sp.w; i3 = 0.0f; }
            else      { i0 = 0.5f * sp.x * np1; i1 = sp.y; i2 = sp.z; i3 = sp.w; }
            v4f pa = *(const v4f*)(btab + boff + f8);
            v4f pb = *(const v4f*)(btab + boff + f8 + 4);
            #pragma unroll
            for (int j = 0; j < 4; j++) {
                pa[j] += i0 * w0a[j] + i1 * w1a[j] + i2 * w2a[j] + i3 * w3a[j];
                pb[j] += i0 * w0b[j] + i1 * w1b[j] + i2 * w2b[j] + i3 * w3b[j];
            }
            v8h hh;
            #pragma unroll
            for (int j = 0; j < 4; j++) {
                hh[j]     = (_Float16)fast_tanh(pa[j]);
                hh[4 + j] = (_Float16)fast_tanh(pb[j]);
            }
            // s in 0..3 -> f8 in {0,8,16,24}+cg*32: 2 threads per (row, 8-feat
            // group)? No: (l15, s) unique -> 4 groups x 8 feats = 32 feats of
            // row l15 per wave; 4 waves cover 128. Each thread writes its v8h.
            *(v8h*)(H0 + l15 * ROWH + f8) = hh;
        }
        __syncthreads();                               // h1 ready

        // ---- forward hidden layer (weights streamed from L2) ----
        auto fwd = [&](auto Lc, const _Float16* hin, _Float16* hout) {
            constexpr int L = decltype(Lc)::value;
            const int lidx = pipe3 + (L - 1);
            v8h wf[2][4];
            #pragma unroll
            for (int n2 = 0; n2 < 2; n2++)
                #pragma unroll
                for (int kk = 0; kk < 4; kk++)
                    wf[n2][kk] = *(const v8h*)(pack + (((lidx * 8 + cg * 2 + n2) * 4 + kk) << 9) + (lane << 3));
            const float* br = btab + boff + L * 128;
            const _Float16* rb = hin + rdo;
            v8h b0 = *(const v8h*)(rb);
            v8h b1 = *(const v8h*)(rb + 32);
            v8h b2 = *(const v8h*)(rb + 64);
            v8h b3 = *(const v8h*)(rb + 96);
            #pragma unroll
            for (int n2 = 0; n2 < 2; n2++) {
                v4f acc = *(const v4f*)(br + fb + n2 * 16);
                acc = __builtin_amdgcn_mfma_f32_16x16x32_f16(wf[n2][0], b0, acc, 0, 0, 0);
                acc = __builtin_amdgcn_mfma_f32_16x16x32_f16(wf[n2][1], b1, acc, 0, 0, 0);
                acc = __builtin_amdgcn_mfma_f32_16x16x32_f16(wf[n2][2], b2, acc, 0, 0, 0);
                acc = __builtin_amdgcn_mfma_f32_16x16x32_f16(wf[n2][3], b3, acc, 0, 0, 0);
                v4h w = {(_Float16)fast_tanh(acc[0]), (_Float16)fast_tanh(acc[1]),
                         (_Float16)fast_tanh(acc[2]), (_Float16)fast_tanh(acc[3])};
                *(v4h*)(hout + epo + n2 * 16) = w;
            }
        };

        fwd(IC<1>{}, H0, H1); __syncthreads();         // h2
        fwd(IC<2>{}, H1, H2); __syncthreads();         // h3

        // ---- fwd3: h4 transient -> V partial + gamma4 = (1-h4^2) .* wout ----
        {
            const int lidx = pipe3 + 2;
            v8h wf[2][4];
            #pragma unroll
            for (int n2 = 0; n2 < 2; n2++)
                #pragma unroll
                for (int kk = 0; kk < 4; kk++)
                    wf[n2][kk] = *(const v8h*)(pack + (((lidx * 8 + cg * 2 + n2) * 4 + kk) << 9) + (lane << 3));
            const float* br = btab + boff + 384;
            const float* wo = woutb + (isic ? 128 : 0);
            const _Float16* rb = H2 + rdo;
            v8h b0 = *(const v8h*)(rb);
            v8h b1 = *(const v8h*)(rb + 32);
            v8h b2 = *(const v8h*)(rb + 64);
            v8h b3 = *(const v8h*)(rb + 96);
            float vp = 0.0f;
            #pragma unroll
            for (int n2 = 0; n2 < 2; n2++) {
                v4f acc = *(const v4f*)(br + fb + n2 * 16);
                acc = __builtin_amdgcn_mfma_f32_16x16x32_f16(wf[n2][0], b0, acc, 0, 0, 0);
                acc = __builtin_amdgcn_mfma_f32_16x16x32_f16(wf[n2][1], b1, acc, 0, 0, 0);
                acc = __builtin_amdgcn_mfma_f32_16x16x32_f16(wf[n2][2], b2, acc, 0, 0, 0);
                acc = __builtin_amdgcn_mfma_f32_16x16x32_f16(wf[n2][3], b3, acc, 0, 0, 0);
                v4f wv = *(const v4f*)(wo + fb + n2 * 16);
                float h0 = fast_tanh(acc[0]), h1 = fast_tanh(acc[1]);
                float h2 = fast_tanh(acc[2]), h3 = fast_tanh(acc[3]);
                vp += h0 * wv[0] + h1 * wv[1] + h2 * wv[2] + h3 * wv[3];
                v4h g = {(_Float16)((1.0f - h0 * h0) * wv[0]),
                         (_Float16)((1.0f - h1 * h1) * wv[1]),
                         (_Float16)((1.0f - h2 * h2) * wv[2]),
                         (_Float16)((1.0f - h3 * h3) * wv[3])};
                *(v4h*)(GA + epo + n2 * 16) = g;
            }
            vp += __shfl_xor(vp, 16);
            vp += __shfl_xor(vp, 32);
            if (lane < 16) vbuf[wave * 16 + lane] = vp;
        }
        __syncthreads();                               // gamma4 + vbuf ready

        // ---- backward layer: gamma_L = D_L .* (W_L^T gamma_{L+1}) ----
        auto bwd = [&](auto Lc, const _Float16* gin, const _Float16* hsrc, _Float16* gout) {
            constexpr int L = decltype(Lc)::value;
            v8h wT[2][4];
            #pragma unroll
            for (int n2 = 0; n2 < 2; n2++)
                #pragma unroll
                for (int kk = 0; kk < 4; kk++)
                    wT[n2][kk] = *(const v8h*)(pack + 98304 + ((((pipe3 + (L - 1)) * 8 + cg * 2 + n2) * 4 + kk) << 9) + (lane << 3));
            const _Float16* rb = gin + rdo;
            v8h b0 = *(const v8h*)(rb);
            v8h b1 = *(const v8h*)(rb + 32);
            v8h b2 = *(const v8h*)(rb + 64);
            v8h b3 = *(const v8h*)(rb + 96);
            #pragma unroll
            for (int n2 = 0; n2 < 2; n2++) {
                v4f acc = {0.f, 0.f, 0.f, 0.f};
                acc = __builtin_amdgcn_mfma_f32_16x16x32_f16(wT[n2][0], b0, acc, 0, 0, 0);
                acc = __builtin_amdgcn_mfma_f32_16x16x32_f16(wT[n2][1], b1, acc, 0, 0, 0);
                acc = __builtin_amdgcn_mfma_f32_16x16x32_f16(wT[n2][2], b2, acc, 0, 0, 0);
                acc = __builtin_amdgcn_mfma_f32_16x16x32_f16(wT[n2][3], b3, acc, 0, 0, 0);
                v4h hv = *(const v4h*)(hsrc + epo + n2 * 16);
                float h0 = (float)hv[0], h1 = (float)hv[1];
                float h2 = (float)hv[2], h3 = (float)hv[3];
                v4h g = {(_Float16)((1.0f - h0 * h0) * acc[0]),
                         (_Float16)((1.0f - h1 * h1) * acc[1]),
                         (_Float16)((1.0f - h2 * h2) * acc[2]),
                         (_Float16)((1.0f - h3 * h3) * acc[3])};
                *(v4h*)(gout + epo + n2 * 16) = g;
            }
        };

        bwd(IC<3>{}, GA, H2, GB); __syncthreads();     // gamma3
        bwd(IC<2>{}, GB, H1, GA); __syncthreads();     // gamma2
        bwd(IC<1>{}, GA, H0, GB); __syncthreads();     // gamma1

        // ---- grad: wave0 = WinSel^T gamma1 (MFMA); wave1 = V sum ----
        {
            float* pbase = part + chunk * 256 + set * 64;
            if (wave == 0) {
                v8h gw[4];
                #pragma unroll
                for (int kk = 0; kk < 4; kk++)
                    gw[kk] = *(const v8h*)(pack + 196608 + ((((isic ? 1 : 0) * 4 + kk)) << 9) + (lane << 3));
                const _Float16* rb = GB + rdo;
                v4f acc = {0.f, 0.f, 0.f, 0.f};
                acc = __builtin_amdgcn_mfma_f32_16x16x32_f16(gw[0], *(const v8h*)(rb),      acc, 0, 0, 0);
                acc = __builtin_amdgcn_mfma_f32_16x16x32_f16(gw[1], *(const v8h*)(rb + 32), acc, 0, 0, 0);
                acc = __builtin_amdgcn_mfma_f32_16x16x32_f16(gw[2], *(const v8h*)(rb + 64), acc, 0, 0, 0);
                acc = __builtin_amdgcn_mfma_f32_16x16x32_f16(gw[3], *(const v8h*)(rb + 96), acc, 0, 0, 0);
                if (lane < 16) {
                    pbase[16 + lane] = acc[0];
                    pbase[32 + lane] = acc[1];
                    pbase[48 + lane] = acc[2];
                }
            } else if (wave == 1 && lane < 16) {
                pbase[lane] = vbuf[lane] + vbuf[16 + lane] + vbuf[32 + lane] + vbuf[48 + lane];
            }
        }
        // no trailing barrier: next L0 writes H0 (last read pre-bar in bwd1);
        // grad reads GB/vbuf, first rewritten >=4 barriers into next unit.
    }
}

// combine: quadrature + envelope + chain rule (exact f32 math as r15-18)
__global__ void node_combine(const float* __restrict__ tx, const float* __restrict__ part,
                             const float* __restrict__ dpBout, const float* __restrict__ icBout,
                             float* __restrict__ outPot, float* __restrict__ outAcc, int N)
{
    int row = blockIdx.x * 256 + threadIdx.x;
    if (row >= N) return;
    float4 q = ((const float4*)tx)[row];
    float t = q.x, x = q.y, y = q.z, z = q.w;
    float r  = sqrtf(x * x + y * y + z * z + 1e-12f);
    float rinv = 1.0f / r;
    float uc = fminf(1.0f, fmaxf(-1.0f, z * rinv));
    float rinv3 = rinv * rinv * rinv;
    float dacos = -1.0f / sqrtf(fmaxf(1.0f - uc * uc, 1e-30f));
    float dthx = dacos * (-x * z * rinv3);
    float dthy = dacos * (-y * z * rinv3);
    float dthz = dacos * (rinv - z * z * rinv3);
    float rho2 = fmaxf(x * x + y * y, 1e-30f);
    float dphx = -y / rho2;
    float dphy =  x / rho2;
    float opr  = 1.0f + r;
    float sEnv = -1.0f / opr;
    float dsdr =  1.0f / (opr * opr);
    float den  = r * r + 0.1f;
    float isq  = 1.0f / sqrtf(den);
    float Aan  = -isq;
    float dAdr = r * isq * isq * isq;

    const float* pr = part + ((row >> 4) << 8) + (row & 15);
    const float wq0 = 0.5555555555555556f, wq1 = 0.8888888888888889f, wq2 = 0.5555555555555556f;
    float dsum = wq0 * pr[0]  + wq1 * pr[64]   + wq2 * pr[128];
    float ds1  = wq0 * pr[16] + wq1 * pr[80]   + wq2 * pr[144];
    float ds2  = wq0 * pr[32] + wq1 * pr[96]   + wq2 * pr[160];
    float ds3  = wq0 * pr[48] + wq1 * pr[112]  + wq2 * pr[176];
    float vic = pr[192], g1 = pr[208], g2 = pr[224], g3 = pr[240];

    float ah = 0.5f * t;
    float tcv  = (vic + icBout[0]) + ah * (dsum + 2.0f * dpBout[0]);
    float dtcr = g1 + ah * ds1;
    float dtct = g2 + ah * ds2;
    float dtcp = g3 + ah * ds3;
    float pot = tcv * sEnv + Aan;
    float gx0 = sEnv * dtcr + tcv * dsdr + dAdr;
    float gx1 = sEnv * dtct;
    float gx2 = sEnv * dtcp;
    float ax = -(gx0 * (x * rinv) + gx1 * dthx + gx2 * dphx);
    float ay = -(gx0 * (y * rinv) + gx1 * dthy + gx2 * dphy);
    float az = -(gx0 * (z * rinv) + gx1 * dthz);
    outPot[row] = pot;
    outAcc[row * 3 + 0] = ax;
    outAcc[row * 3 + 1] = ay;
    outAcc[row * 3 + 2] = az;
}

extern "C" void kernel_launch(void* const* d_in, const int* in_sizes, int n_in,
                              void* d_out, int out_size, void* d_ws, size_t ws_size,
                              hipStream_t stream) {
    (void)n_in; (void)out_size;
    const float* tx     = (const float*)d_in[0];
    const float* dpWin  = (const float*)d_in[1];
    const float* dpBin  = (const float*)d_in[2];
    const float* dpWh   = (const float*)d_in[3];
    const float* dpBh   = (const float*)d_in[4];
    const float* dpWout = (const float*)d_in[5];
    const float* dpBout = (const float*)d_in[6];
    const float* icWin  = (const float*)d_in[7];
    const float* icBin  = (const float*)d_in[8];
    const float* icWh   = (const float*)d_in[9];
    const float* icBh   = (const float*)d_in[10];
    const float* icWout = (const float*)d_in[11];
    const float* icBout = (const float*)d_in[12];

    int N = in_sizes[0] / 4;
    int chunks = (N + 15) >> 4;
    size_t part_bytes = (size_t)chunks * 256 * sizeof(float);
    size_t sph_off = (size_t)PACK_BYTES + part_bytes;
    size_t need = sph_off + (size_t)N * 4 * sizeof(float);
    if (ws_size < need) return;
    _Float16* pack = (_Float16*)d_ws;
    float* part = (float*)((char*)d_ws + PACK_BYTES);
    float* sph  = (float*)((char*)d_ws + sph_off);
    float* outPot = (float*)d_out;
    float* outAcc = outPot + N;

    pack_weights<<<(200704 + 255) / 256, 256, 0, stream>>>(dpWh, icWh, dpWin, icWin, pack);
    sph_prep<<<(N + 255) / 256, 256, 0, stream>>>(tx, sph, N);

    (void)hipFuncSetAttribute(reinterpret_cast<const void*>(node_main),
                              hipFuncAttributeMaxDynamicSharedMemorySize, SMEM_BYTES);
    node_main<<<1280, 256, SMEM_BYTES, stream>>>(sph,
        dpBin, dpBh, icBin, icBh, dpWin, icWin, dpWout, icWout,
        pack, part, N);

    node_combine<<<(N + 255) / 256, 256, 0, stream>>>(tx, part, dpBout, icBout,
                                                      outPot, outAcc, N);
}